// Round 4
// baseline (424.809 us; speedup 1.0000x reference)
//
#include <hip/hip_runtime.h>
#include <stdint.h>

#define B_ 2
#define T_ 2048
#define P_ 1024
#define H_ 16
#define D_ 128
#define C_ 2048
#define S_ 3072   // P_ + T_
#define M_ 4096   // B_*T_
#define N3_ 6144  // 3*C_

typedef unsigned short u16;
typedef unsigned int uint32;
typedef __attribute__((ext_vector_type(8))) short short8;
typedef __attribute__((ext_vector_type(8))) __bf16 bf16x8;
typedef __attribute__((ext_vector_type(4))) float f32x4;
typedef __attribute__((ext_vector_type(16))) float f32x16;
typedef __attribute__((ext_vector_type(4))) unsigned short u16x4;
typedef __attribute__((ext_vector_type(4))) unsigned int uint4v;

static __device__ __forceinline__ float bf2f(u16 h) {
    union { unsigned int u; float f; } x; x.u = ((unsigned int)h) << 16; return x.f;
}
static __device__ __forceinline__ u16 f2bf(float f) {
    return __builtin_bit_cast(u16, (__bf16)f);   // v_cvt: RNE, 1 op
}
static __device__ __forceinline__ uint32 pkbf(float x, float y) {
    return (uint32)f2bf(x) | ((uint32)f2bf(y) << 16);
}

static __device__ __forceinline__ f32x4 mfma_bf16(short8 a, short8 b, f32x4 c) {
    return __builtin_amdgcn_mfma_f32_16x16x32_bf16(
        __builtin_bit_cast(bf16x8, a), __builtin_bit_cast(bf16x8, b), c, 0, 0, 0);
}
static __device__ __forceinline__ f32x16 mfma32(short8 a, short8 b, f32x16 c) {
    return __builtin_amdgcn_mfma_f32_32x32x16_bf16(
        __builtin_bit_cast(bf16x8, a), __builtin_bit_cast(bf16x8, b), c, 0, 0, 0);
}

typedef __attribute__((address_space(3))) unsigned int lds_u32;
typedef const __attribute__((address_space(1))) unsigned int glb_u32;
static __device__ __forceinline__ void gload_lds16(const void* g, void* l) {
    __builtin_amdgcn_global_load_lds((glb_u32*)g, (lds_u32*)l, 16, 0, 0);
}

static __device__ __forceinline__ void storeC(float* p, float v) { *p = v; }
static __device__ __forceinline__ void storeC(u16* p, float v) { *p = f2bf(v); }

// ---------------------------------------------------------------- prep kernels

__global__ void castx_kernel(const float* __restrict__ x, u16* __restrict__ Xb) {
    int idx = blockIdx.x * 256 + threadIdx.x;          // over (M_*C_)/4
    const float4 v = ((const float4*)x)[idx];
    u16x4 o;
    o.x = f2bf(v.x); o.y = f2bf(v.y); o.z = f2bf(v.z); o.w = f2bf(v.w);
    ((u16x4*)Xb)[idx] = o;
}

// W[K,N] f32 -> Wt[N,K] bf16, 64x64 LDS tiles
__global__ void wT_kernel(const float* __restrict__ W, u16* __restrict__ Wt,
                          int Ndim, int Kdim) {
    __shared__ float tile[64][65];
    const int n0 = blockIdx.x * 64, k0 = blockIdx.y * 64;
    const int tid = threadIdx.x;
#pragma unroll
    for (int i = 0; i < 16; i++) {
        int idx = tid + i * 256;
        int r = idx >> 6, c = idx & 63;                // r: k, c: n
        tile[r][c] = W[(size_t)(k0 + r) * Ndim + n0 + c];
    }
    __syncthreads();
#pragma unroll
    for (int i = 0; i < 16; i++) {
        int idx = tid + i * 256;
        int r = idx >> 6, c = idx & 63;                // r: n, c: k
        Wt[(size_t)(n0 + r) * Kdim + k0 + c] = f2bf(tile[c][r]);
    }
}

__global__ void rope_table_kernel(float* __restrict__ cosT, float* __restrict__ sinT) {
    int idx = blockIdx.x * 256 + threadIdx.x;          // T_*64
    int t = idx >> 6, d = idx & 63;
    float inv = powf(10000.0f, -(float)d * (1.0f / 64.0f));
    float ang = (float)(P_ + t) * inv;
    cosT[idx] = cosf(ang);
    sinT[idx] = sinf(ang);
}

// RoPE Q in place; RoPE K and scatter into Kc[b,h,P_+t,d]
__global__ void rope_qk_kernel(u16* __restrict__ QKVb, u16* __restrict__ Kc,
                               const float* __restrict__ cosT,
                               const float* __restrict__ sinT) {
    int idx = blockIdx.x * 256 + threadIdx.x;          // B_*T_*H_*64
    int d = idx & 63;
    int h = (idx >> 6) & 15;
    int t = (idx >> 10) & 2047;
    int b = idx >> 21;
    size_t rowoff = (size_t)(b * T_ + t) * N3_;
    float c = cosT[(t << 6) + d], s = sinT[(t << 6) + d];
    {   // Q
        u16* p1 = QKVb + rowoff + h * 128 + d;
        float x1 = bf2f(p1[0]), x2 = bf2f(p1[64]);
        p1[0]  = f2bf(x1 * c - x2 * s);
        p1[64] = f2bf(x2 * c + x1 * s);
    }
    {   // K -> cache
        const u16* p1 = QKVb + rowoff + C_ + h * 128 + d;
        float x1 = bf2f(p1[0]), x2 = bf2f(p1[64]);
        u16* o = Kc + ((size_t)(b * H_ + h) * S_ + P_ + t) * 128 + d;
        o[0]  = f2bf(x1 * c - x2 * s);
        o[64] = f2bf(x2 * c + x1 * s);
    }
}

__global__ void pastk_kernel(const float* __restrict__ past_k, u16* __restrict__ Kc) {
    int idx = blockIdx.x * 256 + threadIdx.x;          // B_*H_*P_*D_
    int d = idx & 127;
    int p = (idx >> 7) & 1023;
    int bh = idx >> 17;
    Kc[((size_t)bh * S_ + p) * 128 + d] = f2bf(past_k[idx]);
}

// new V (bf16 in QKVb) -> Vt[b,h,d,P_+t]
__global__ void vnewT_kernel(const u16* __restrict__ QKVb, u16* __restrict__ Vt) {
    __shared__ u16 tile[64][65];
    const int t0 = blockIdx.x * 64, d0 = blockIdx.y * 64, bh = blockIdx.z;
    const int b = bh >> 4, h = bh & 15;
    const int tid = threadIdx.x;
#pragma unroll
    for (int i = 0; i < 16; i++) {
        int idx = tid + i * 256;
        int r = idx >> 6, c = idx & 63;                // r: t, c: d
        tile[r][c] = QKVb[(size_t)(b * T_ + t0 + r) * N3_ + 2 * C_ + h * 128 + d0 + c];
    }
    __syncthreads();
#pragma unroll
    for (int i = 0; i < 16; i++) {
        int idx = tid + i * 256;
        int r = idx >> 6, c = idx & 63;                // r: d, c: t
        Vt[((size_t)bh * 128 + d0 + r) * S_ + P_ + t0 + c] = tile[c][r];
    }
}

// past V f32 -> Vt[b,h,d,p]
__global__ void vpastT_kernel(const float* __restrict__ past_v, u16* __restrict__ Vt) {
    __shared__ float tile[64][65];
    const int p0 = blockIdx.x * 64, d0 = blockIdx.y * 64, bh = blockIdx.z;
    const int tid = threadIdx.x;
#pragma unroll
    for (int i = 0; i < 16; i++) {
        int idx = tid + i * 256;
        int r = idx >> 6, c = idx & 63;                // r: p, c: d
        tile[r][c] = past_v[((size_t)bh * P_ + p0 + r) * 128 + d0 + c];
    }
    __syncthreads();
#pragma unroll
    for (int i = 0; i < 16; i++) {
        int idx = tid + i * 256;
        int r = idx >> 6, c = idx & 63;                // r: d, c: p
        Vt[((size_t)bh * 128 + d0 + r) * S_ + p0 + c] = f2bf(tile[c][r]);
    }
}

// ---------------------------------------------------------------- GEMM 128^2
// C[M,N] = A[M,K] * Bt[N,K]^T ; bf16 in, OutT out. 128x128 tile, BK=64, 4 waves.
template <typename OutT>
__global__ void __launch_bounds__(256)
gemm_bt(const u16* __restrict__ A, const u16* __restrict__ Bt,
        OutT* __restrict__ Co, int Mdim, int Ndim, int Kdim) {
    __shared__ u16 ldsA[128 * 64];
    __shared__ u16 ldsB[128 * 64];
    const int nbx = Ndim >> 7;
    const int nwg = (Mdim >> 7) * nbx;
    int bid = blockIdx.x;
    int wg = (bid & 7) * (nwg >> 3) + (bid >> 3);      // XCD swizzle (nwg % 8 == 0)
    const int bm = wg / nbx, bn = wg % nbx;
    const int m0 = bm << 7, n0 = bn << 7;
    const int tid = threadIdx.x;
    const int wave = tid >> 6, lane = tid & 63;
    const int wr = wave >> 1, wc = wave & 1;

    f32x4 acc[4][4];
#pragma unroll
    for (int i = 0; i < 4; i++)
#pragma unroll
        for (int j = 0; j < 4; j++) acc[i][j] = (f32x4){0.f, 0.f, 0.f, 0.f};

    const int srow = wave * 32 + (lane >> 3);
    const int scol = (lane & 7) << 3;
    const u16* gA = A + (size_t)(m0 + srow) * Kdim + scol;
    const u16* gB = Bt + (size_t)(n0 + srow) * Kdim + scol;

    for (int k0 = 0; k0 < Kdim; k0 += 64) {
#pragma unroll
        for (int c = 0; c < 4; c++) {
            gload_lds16(gA + (size_t)(c * 8) * Kdim + k0, &ldsA[(wave * 32 + c * 8) * 64]);
            gload_lds16(gB + (size_t)(c * 8) * Kdim + k0, &ldsB[(wave * 32 + c * 8) * 64]);
        }
        __syncthreads();
#pragma unroll
        for (int kk = 0; kk < 2; kk++) {
            short8 af[4], bf[4];
#pragma unroll
            for (int i = 0; i < 4; i++) {
                int row = wr * 64 + i * 16 + (lane & 15);
                af[i] = *(const short8*)&ldsA[row * 64 + kk * 32 + ((lane >> 4) << 3)];
                int col = wc * 64 + i * 16 + (lane & 15);
                bf[i] = *(const short8*)&ldsB[col * 64 + kk * 32 + ((lane >> 4) << 3)];
            }
#pragma unroll
            for (int i = 0; i < 4; i++)
#pragma unroll
                for (int j = 0; j < 4; j++)
                    acc[i][j] = mfma_bf16(af[i], bf[j], acc[i][j]);
        }
        __syncthreads();
    }
#pragma unroll
    for (int i = 0; i < 4; i++)
#pragma unroll
        for (int j = 0; j < 4; j++) {
            int row = m0 + wr * 64 + i * 16 + ((lane >> 4) << 2);
            int col = n0 + wc * 64 + j * 16 + (lane & 15);
#pragma unroll
            for (int q = 0; q < 4; q++)
                storeC(&Co[(size_t)(row + q) * Ndim + col], acc[i][j][q]);
        }
}

// ---------------------------------------------------------------- GEMM 256^2
// 8-phase template (T2+T3+T4+T5). 512 thr = 8 waves (2m x 4n); per-wave C =
// 128x64. BK=64, dbuf LDS 128 KiB. Staging: all 8 gload_lds burst at phase 0
// (~3 phases before the single vmcnt(0) at tile end -> HBM latency covered;
// never a drain right after issue). Raw s_barrier per phase (no implicit
// vmcnt drain); asm memory fences pin cross-buffer ds_reads below barriers.
// LDS XOR-swizzle ((row&7)<<4) applied via pre-swizzled global source
// (linear LDS dest, rule #21) and on every ds_read.
template <typename OutT>
__global__ void __launch_bounds__(512, 1)
gemm256(const u16* __restrict__ A, const u16* __restrict__ Bt,
        OutT* __restrict__ Co, int Mdim, int Ndim, int Kdim) {
    __shared__ u16 lA[2][256 * 64];
    __shared__ u16 lB[2][256 * 64];
    const int nbx = Ndim >> 8;
    const int nwg = (Mdim >> 8) * nbx;
    int bid = blockIdx.x;
    int wg = (bid & 7) * (nwg >> 3) + (bid >> 3);      // nwg % 8 == 0
    const int bm = wg / nbx, bn = wg % nbx;
    const int m0 = bm << 8, n0 = bn << 8;
    const int tid = threadIdx.x;
    const int wave = tid >> 6, lane = tid & 63;
    const int mw = wave >> 2, nw = wave & 3;
    const int l15 = lane & 15, l4 = lane >> 4;
    const int sw = (l15 & 7) << 4;                     // read-side swizzle (bytes)

    f32x4 acc[8][4];
#pragma unroll
    for (int i = 0; i < 8; i++)
#pragma unroll
        for (int j = 0; j < 4; j++) acc[i][j] = (f32x4){0.f, 0.f, 0.f, 0.f};

    // staging: wave stages ONLY its own halves (A rows mw*128..+128 with the
    // 3 other waves sharing mw; B rows bw*128..+128 with its 3 sharers).
    const int bw = nw >> 1, bx4 = mw * 2 + (nw & 1);
    const u16* asrc[4];
    const u16* bsrc[4];
    int adst[4], bdst[4];
#pragma unroll
    for (int c = 0; c < 4; c++) {
        int cid = nw * 256 + c * 64 + lane;            // chunk in A-half
        int row = cid >> 3, colc = cid & 7;
        asrc[c] = A + (size_t)(m0 + mw * 128 + row) * Kdim
                  + ((((colc << 4) ^ ((row & 7) << 4)) >> 1));
        adst[c] = mw * 8192 + (nw * 256 + c * 64) * 8; // u16 units, wave-uniform
        cid = bx4 * 256 + c * 64 + lane;               // chunk in B-half
        row = cid >> 3; colc = cid & 7;
        bsrc[c] = Bt + (size_t)(n0 + bw * 128 + row) * Kdim
                  + ((((colc << 4) ^ ((row & 7) << 4)) >> 1));
        bdst[c] = bw * 8192 + (bx4 * 256 + c * 64) * 8;
    }

#define STAGE256(bufi, kt) do {                                                 \
    _Pragma("unroll")                                                           \
    for (int c = 0; c < 4; c++) {                                               \
        gload_lds16(asrc[c] + (size_t)(kt) * 64, &lA[bufi][adst[c]]);           \
        gload_lds16(bsrc[c] + (size_t)(kt) * 64, &lB[bufi][bdst[c]]);           \
    }                                                                           \
} while (0)

    // prologue
    STAGE256(0, 0);
    asm volatile("s_waitcnt vmcnt(0)" ::: "memory");
    __builtin_amdgcn_s_barrier();
    asm volatile("" ::: "memory");

    const int NT = Kdim >> 6;
    for (int t = 0; t < NT; ++t) {
        const int cur = t & 1;
        const u16* la = lA[cur];
        const u16* lb = lB[cur];
        short8 bfr[4][2];
#pragma unroll
        for (int p = 0; p < 4; p++) {
            if (p == 0 && t + 1 < NT) STAGE256(cur ^ 1, t + 1);
            short8 af[2][2];
#pragma unroll
            for (int i = 0; i < 2; i++)
#pragma unroll
                for (int kk = 0; kk < 2; kk++) {
                    int row = mw * 128 + (p * 2 + i) * 16 + l15;
                    int colb = ((kk << 6) + (l4 << 4)) ^ sw;
                    af[i][kk] = *(const short8*)&la[row * 64 + (colb >> 1)];
                }
            if (p == 0) {
#pragma unroll
                for (int nf = 0; nf < 4; nf++)
#pragma unroll
                    for (int kk = 0; kk < 2; kk++) {
                        int row = nw * 64 + nf * 16 + l15;
                        int colb = ((kk << 6) + (l4 << 4)) ^ sw;
                        bfr[nf][kk] = *(const short8*)&lb[row * 64 + (colb >> 1)];
                    }
            }
            __builtin_amdgcn_s_barrier();
            asm volatile("s_waitcnt lgkmcnt(0)" ::: "memory");
            __builtin_amdgcn_s_setprio(1);
#pragma unroll
            for (int i = 0; i < 2; i++)
#pragma unroll
                for (int nf = 0; nf < 4; nf++)
#pragma unroll
                    for (int kk = 0; kk < 2; kk++)
                        acc[p * 2 + i][nf] = mfma_bf16(af[i][kk], bfr[nf][kk],
                                                       acc[p * 2 + i][nf]);
            __builtin_amdgcn_s_setprio(0);
            if (p == 3) asm volatile("s_waitcnt vmcnt(0)" ::: "memory");
            __builtin_amdgcn_s_barrier();
            asm volatile("" ::: "memory");
        }
    }
#undef STAGE256

    // epilogue
#pragma unroll
    for (int mf = 0; mf < 8; mf++)
#pragma unroll
        for (int nf = 0; nf < 4; nf++) {
            int row = m0 + mw * 128 + mf * 16 + l4 * 4;
            int col = n0 + nw * 64 + nf * 16 + l15;
#pragma unroll
            for (int q = 0; q < 4; q++)
                storeC(&Co[(size_t)(row + q) * Ndim + col], acc[mf][nf][q]);
        }
}

// ---------------------------------------------------------------- attention
// m214-style: 8 waves x 32 q-rows = 256 q/block; one (b,h) slice per block.
// Swapped QK^T (mfma(K,Q)): P C-frag has q = lane&31, k reg-mapped -> softmax
// fully in-register (1 shfl_xor(32) per reduce). Swapped PV (mfma(V^T,P^T)):
// O^T C-frag has q = lane&31 -> rescale factor lane-local. No P LDS buffer.
// K/V double-buffered LDS, XOR-swizzle ((row&7)<<4) both-sides (rule #21).
__global__ void __launch_bounds__(512, 2)
attn_kernel(const u16* __restrict__ QKVb, const u16* __restrict__ Kc,
            const u16* __restrict__ Vt, u16* __restrict__ O) {
    __shared__ u16 ldsK[2][64 * 128];   // [buf][64 k][128 d], rows 256B
    __shared__ u16 ldsV[2][128 * 64];   // [buf][128 d][64 k], rows 128B

    int bid = blockIdx.x;                              // 256 blocks
    int wg = (bid & 7) * 32 + (bid >> 3);              // XCD swizzle (bijective)
    const int qc = wg & 7;                             // q-chunk (8 x 256 rows)
    const int bh = wg >> 3;
    const int b = bh >> 4, h = bh & 15;
    const int tid = threadIdx.x, wave = tid >> 6, lane = tid & 63;
    const int l31 = lane & 31, hi = lane >> 5;

    // staging constants (source pre-swizzled; LDS dest linear)
    const int krow = tid >> 4;                                         // 0..31
    const int kcol = (((tid & 15) << 4) ^ ((krow & 7) << 4)) >> 1;
    const int vrow = tid >> 3;                                         // 0..63
    const int vcol = (((tid & 7) << 4) ^ ((vrow & 7) << 4)) >> 1;

    const u16* Kbh = Kc + (size_t)bh * S_ * 128;
    const u16* Vbh = Vt + (size_t)bh * 128 * S_;

    const int tq = qc * 256 + wave * 32 + l31;         // this lane's q row
    // Q fragments: Q[q=l31][d = ks*16 + hi*8 + e], 8 x bf16x8
    short8 qf[8];
    {
        const u16* qp = QKVb + (size_t)(b * T_ + tq) * N3_ + h * 128 + hi * 8;
#pragma unroll
        for (int ks = 0; ks < 8; ks++) qf[ks] = *(const short8*)(qp + ks * 16);
    }

    f32x16 acco[4];                                    // O^T: col q=l31, row d
#pragma unroll
    for (int d = 0; d < 4; d++) acco[d] = (f32x16)(0.0f);
    float mrow = -1e30f, lrow = 0.f;                   // per-lane (q = l31)
    const float sl2 = 0.08838834764831845f * 1.4426950408889634f;

#define STAGE(bufi, tt) do {                                                    \
    const int _s0 = (tt) * 64;                                                  \
    gload_lds16(Kbh + (size_t)(_s0 + krow) * 128 + kcol,                        \
                (char*)&ldsK[bufi][0] + wave * 1024);                           \
    gload_lds16(Kbh + (size_t)(_s0 + krow + 32) * 128 + kcol,                   \
                (char*)&ldsK[bufi][0] + 8192 + wave * 1024);                    \
    gload_lds16(Vbh + (size_t)vrow * S_ + _s0 + vcol,                           \
                (char*)&ldsV[bufi][0] + wave * 1024);                           \
    gload_lds16(Vbh + (size_t)(vrow + 64) * S_ + _s0 + vcol,                    \
                (char*)&ldsV[bufi][0] + 8192 + wave * 1024);                    \
} while (0)

    STAGE(0, 0);
    __syncthreads();

    const int swz = (l31 & 7) << 4;                    // read-side swizzle

    for (int t = 0; t < S_ / 64; ++t) {
        const int cur = t & 1;
        if (t < S_ / 64 - 1) STAGE(cur ^ 1, t + 1);

        const u16* Kl = ldsK[cur];
        const u16* Vl = ldsV[cur];

        // ---- QK^T: p0 (k 0..31), p1 (k 32..63); contraction d ----
        f32x16 p0 = (f32x16)(0.0f), p1 = (f32x16)(0.0f);
        __builtin_amdgcn_s_setprio(1);
#pragma unroll
        for (int ks = 0; ks < 8; ks++) {
            const int cidx = (((ks * 32 + hi * 16) ^ swz) >> 1);
            short8 k0 = *(const short8*)&Kl[(l31 << 7) + cidx];
            short8 k1 = *(const short8*)&Kl[((32 + l31) << 7) + cidx];
            p0 = mfma32(k0, qf[ks], p0);
            p1 = mfma32(k1, qf[ks], p1);
        }
        __builtin_amdgcn_s_setprio(0);

        // ---- online softmax, in-register (q = l31) ----
        float pm = fmaxf(p0[0], p0[1]);
#pragma unroll
        for (int r = 2; r < 16; r++) pm = fmaxf(pm, p0[r]);
#pragma unroll
        for (int r = 0; r < 16; r++) pm = fmaxf(pm, p1[r]);
        pm = fmaxf(pm, __shfl_xor(pm, 32));
        float pmS = pm * sl2;
        if (!__all(pmS <= mrow + 8.0f)) {              // T13 defer-max
            float mn = fmaxf(mrow, pmS);
            float fac = exp2f(mrow - mn);
            mrow = mn;
            lrow *= fac;
#pragma unroll
            for (int d = 0; d < 4; d++)
#pragma unroll
                for (int r = 0; r < 16; r++) acco[d][r] *= fac;
        }
        float sum = 0.f;
#pragma unroll
        for (int r = 0; r < 16; r++) { p0[r] = exp2f(fmaf(p0[r], sl2, -mrow)); sum += p0[r]; }
#pragma unroll
        for (int r = 0; r < 16; r++) { p1[r] = exp2f(fmaf(p1[r], sl2, -mrow)); sum += p1[r]; }
        sum += __shfl_xor(sum, 32);
        lrow += sum;

        // ---- P (C-layout) -> PV B-frags, in-register (T12 via shfl) ----
        // k_local(reg,hi) = (reg&3) + 8*(reg>>2) + 4*hi; frag e -> k = ks*16+hi*8+e
        uint32 w[4][4];
#define PACK_HALF(pp, kh, ksout) do {                                           \
    uint32 A0 = pkbf(pp[(kh)*8 + 0], pp[(kh)*8 + 1]);                           \
    uint32 A1 = pkbf(pp[(kh)*8 + 2], pp[(kh)*8 + 3]);                           \
    uint32 B0 = pkbf(pp[(kh)*8 + 4], pp[(kh)*8 + 5]);                           \
    uint32 B1 = pkbf(pp[(kh)*8 + 6], pp[(kh)*8 + 7]);                           \
    uint32 sA0 = __shfl_xor(A0, 32), sA1 = __shfl_xor(A1, 32);                  \
    uint32 sB0 = __shfl_xor(B0, 32), sB1 = __shfl_xor(B1, 32);                  \
    w[ksout][0] = hi ? sB0 : A0;                                                \
    w[ksout][1] = hi ? sB1 : A1;                                                \
    w[ksout][2] = hi ? B0 : sA0;                                                \
    w[ksout][3] = hi ? B1 : sA1;                                                \
} while (0)
        PACK_HALF(p0, 0, 0);
        PACK_HALF(p0, 1, 1);
        PACK_HALF(p1, 0, 2);
        PACK_HALF(p1, 1, 3);
#undef PACK_HALF

        // ---- PV: O^T[d][q] += V^T[d][k] * P^T[k][q] ----
        __builtin_amdgcn_s_setprio(1);
#pragma unroll
        for (int ks = 0; ks < 4; ks++) {
            uint4v pw = {w[ks][0], w[ks][1], w[ks][2], w[ks][3]};
            short8 pf = __builtin_bit_cast(short8, pw);
            const int cidx = (((ks * 32 + hi * 16) ^ swz) >> 1);
#pragma unroll
            for (int dblk = 0; dblk < 4; dblk++) {
                short8 vf = *(const short8*)&Vl[((dblk * 32 + l31) << 6) + cidx];
                acco[dblk] = mfma32(vf, pf, acco[dblk]);
            }
        }
        __builtin_amdgcn_s_setprio(0);

        __syncthreads();   // readers done with cur; stage(cur^1) drained
    }
#undef STAGE

    // ---- epilogue: O[b*T+tq][h*128+d], d = dblk*32 + 8*j + 4*hi + {0..3} ----
    float rl = 1.0f / lrow;
    u16* Op = O + (size_t)(b * T_ + tq) * C_ + h * 128;
#pragma unroll
    for (int dblk = 0; dblk < 4; dblk++)
#pragma unroll
        for (int j = 0; j < 4; j++) {
            u16x4 o;
            o.x = f2bf(acco[dblk][4 * j + 0] * rl);
            o.y = f2bf(acco[dblk][4 * j + 1] * rl);
            o.z = f2bf(acco[dblk][4 * j + 2] * rl);
            o.w = f2bf(acco[dblk][4 * j + 3] * rl);
            *(u16x4*)(Op + dblk * 32 + j * 8 + hi * 4) = o;
        }
}

// ---------------------------------------------------------------- launch

extern "C" void kernel_launch(void* const* d_in, const int* in_sizes, int n_in,
                              void* d_out, int out_size, void* d_ws, size_t ws_size,
                              hipStream_t stream) {
    const float* x      = (const float*)d_in[0];
    const float* w_qkv  = (const float*)d_in[1];
    const float* w_out  = (const float*)d_in[2];
    const float* past_k = (const float*)d_in[3];
    const float* past_v = (const float*)d_in[4];
    float* out = (float*)d_out;

    char* ws = (char*)d_ws;
    u16* Xb    = (u16*)(ws);                            // 16 MB
    u16* Wqkvt = (u16*)(ws + 16777216);                 // 24 MB
    u16* Woutt = (u16*)(ws + 41943040);                 //  8 MB
    u16* QKVb  = (u16*)(ws + 50331648);                 // 48 MB
    u16* Kc    = (u16*)(ws + 100663296);                // 24 MB
    u16* Vt    = (u16*)(ws + 125829120);                // 24 MB
    u16* O     = (u16*)(ws + 150994944);                // 16 MB
    float* cosT = (float*)(ws + 167772160);             // 0.5 MB
    float* sinT = (float*)(ws + 168296448);             // 0.5 MB

    castx_kernel<<<(M_ * C_ / 4) / 256, 256, 0, stream>>>(x, Xb);
    wT_kernel<<<dim3(N3_ / 64, C_ / 64), 256, 0, stream>>>(w_qkv, Wqkvt, N3_, C_);
    wT_kernel<<<dim3(C_ / 64, C_ / 64), 256, 0, stream>>>(w_out, Woutt, C_, C_);
    rope_table_kernel<<<(T_ * 64) / 256, 256, 0, stream>>>(cosT, sinT);

    gemm256<u16><<<(M_ / 256) * (N3_ / 256), 512, 0, stream>>>(Xb, Wqkvt, QKVb, M_, N3_, C_);

    rope_qk_kernel<<<(B_ * T_ * H_ * 64) / 256, 256, 0, stream>>>(QKVb, Kc, cosT, sinT);
    pastk_kernel<<<(B_ * H_ * P_ * D_) / 256, 256, 0, stream>>>(past_k, Kc);
    vnewT_kernel<<<dim3(T_ / 64, 2, B_ * H_), 256, 0, stream>>>(QKVb, Vt);
    vpastT_kernel<<<dim3(P_ / 64, 2, B_ * H_), 256, 0, stream>>>(past_v, Vt);

    attn_kernel<<<256, 512, 0, stream>>>(QKVb, Kc, Vt, O);

    gemm_bt<float><<<(M_ / 128) * (C_ / 128), 256, 0, stream>>>(O, Woutt, out, M_, C_, C_);
}

// Round 5
// 399.842 us; speedup vs baseline: 1.0624x; 1.0624x over previous
//
#include <hip/hip_runtime.h>
#include <stdint.h>

#define B_ 2
#define T_ 2048
#define P_ 1024
#define H_ 16
#define D_ 128
#define C_ 2048
#define S_ 3072   // P_ + T_
#define M_ 4096   // B_*T_
#define N3_ 6144  // 3*C_

typedef unsigned short u16;
typedef unsigned int uint32;
typedef __attribute__((ext_vector_type(8))) short short8;
typedef __attribute__((ext_vector_type(8))) __bf16 bf16x8;
typedef __attribute__((ext_vector_type(4))) float f32x4;
typedef __attribute__((ext_vector_type(16))) float f32x16;
typedef __attribute__((ext_vector_type(4))) unsigned short u16x4;
typedef __attribute__((ext_vector_type(4))) unsigned int uint4v;

static __device__ __forceinline__ float bf2f(u16 h) {
    union { unsigned int u; float f; } x; x.u = ((unsigned int)h) << 16; return x.f;
}
static __device__ __forceinline__ u16 f2bf(float f) {
    return __builtin_bit_cast(u16, (__bf16)f);   // v_cvt: RNE, 1 op
}
static __device__ __forceinline__ uint32 pkbf(float x, float y) {
    return (uint32)f2bf(x) | ((uint32)f2bf(y) << 16);
}

static __device__ __forceinline__ f32x4 mfma_bf16(short8 a, short8 b, f32x4 c) {
    return __builtin_amdgcn_mfma_f32_16x16x32_bf16(
        __builtin_bit_cast(bf16x8, a), __builtin_bit_cast(bf16x8, b), c, 0, 0, 0);
}
static __device__ __forceinline__ f32x16 mfma32(short8 a, short8 b, f32x16 c) {
    return __builtin_amdgcn_mfma_f32_32x32x16_bf16(
        __builtin_bit_cast(bf16x8, a), __builtin_bit_cast(bf16x8, b), c, 0, 0, 0);
}

typedef __attribute__((address_space(3))) unsigned int lds_u32;
typedef const __attribute__((address_space(1))) unsigned int glb_u32;
static __device__ __forceinline__ void gload_lds16(const void* g, void* l) {
    __builtin_amdgcn_global_load_lds((glb_u32*)g, (lds_u32*)l, 16, 0, 0);
}

static __device__ __forceinline__ void storeC(float* p, float v) { *p = v; }
static __device__ __forceinline__ void storeC(u16* p, float v) { *p = f2bf(v); }

// ---------------------------------------------------------------- prep kernels

__global__ void castx_kernel(const float* __restrict__ x, u16* __restrict__ Xb) {
    int idx = blockIdx.x * 256 + threadIdx.x;          // over (M_*C_)/4
    const float4 v = ((const float4*)x)[idx];
    u16x4 o;
    o.x = f2bf(v.x); o.y = f2bf(v.y); o.z = f2bf(v.z); o.w = f2bf(v.w);
    ((u16x4*)Xb)[idx] = o;
}

// W[K,N] f32 -> Wt[N,K] bf16, 64x64 LDS tiles
__global__ void wT_kernel(const float* __restrict__ W, u16* __restrict__ Wt,
                          int Ndim, int Kdim) {
    __shared__ float tile[64][65];
    const int n0 = blockIdx.x * 64, k0 = blockIdx.y * 64;
    const int tid = threadIdx.x;
#pragma unroll
    for (int i = 0; i < 16; i++) {
        int idx = tid + i * 256;
        int r = idx >> 6, c = idx & 63;                // r: k, c: n
        tile[r][c] = W[(size_t)(k0 + r) * Ndim + n0 + c];
    }
    __syncthreads();
#pragma unroll
    for (int i = 0; i < 16; i++) {
        int idx = tid + i * 256;
        int r = idx >> 6, c = idx & 63;                // r: n, c: k
        Wt[(size_t)(n0 + r) * Kdim + k0 + c] = f2bf(tile[c][r]);
    }
}

__global__ void rope_table_kernel(float* __restrict__ cosT, float* __restrict__ sinT) {
    int idx = blockIdx.x * 256 + threadIdx.x;          // T_*64
    int t = idx >> 6, d = idx & 63;
    float inv = powf(10000.0f, -(float)d * (1.0f / 64.0f));
    float ang = (float)(P_ + t) * inv;
    cosT[idx] = cosf(ang);
    sinT[idx] = sinf(ang);
}

// RoPE Q in place; RoPE K and scatter into Kc[b,h,P_+t,d]
__global__ void rope_qk_kernel(u16* __restrict__ QKVb, u16* __restrict__ Kc,
                               const float* __restrict__ cosT,
                               const float* __restrict__ sinT) {
    int idx = blockIdx.x * 256 + threadIdx.x;          // B_*T_*H_*64
    int d = idx & 63;
    int h = (idx >> 6) & 15;
    int t = (idx >> 10) & 2047;
    int b = idx >> 21;
    size_t rowoff = (size_t)(b * T_ + t) * N3_;
    float c = cosT[(t << 6) + d], s = sinT[(t << 6) + d];
    {   // Q
        u16* p1 = QKVb + rowoff + h * 128 + d;
        float x1 = bf2f(p1[0]), x2 = bf2f(p1[64]);
        p1[0]  = f2bf(x1 * c - x2 * s);
        p1[64] = f2bf(x2 * c + x1 * s);
    }
    {   // K -> cache
        const u16* p1 = QKVb + rowoff + C_ + h * 128 + d;
        float x1 = bf2f(p1[0]), x2 = bf2f(p1[64]);
        u16* o = Kc + ((size_t)(b * H_ + h) * S_ + P_ + t) * 128 + d;
        o[0]  = f2bf(x1 * c - x2 * s);
        o[64] = f2bf(x2 * c + x1 * s);
    }
}

__global__ void pastk_kernel(const float* __restrict__ past_k, u16* __restrict__ Kc) {
    int idx = blockIdx.x * 256 + threadIdx.x;          // B_*H_*P_*D_
    int d = idx & 127;
    int p = (idx >> 7) & 1023;
    int bh = idx >> 17;
    Kc[((size_t)bh * S_ + p) * 128 + d] = f2bf(past_k[idx]);
}

// new V (bf16 in QKVb) -> Vt[b,h,d,P_+t]
__global__ void vnewT_kernel(const u16* __restrict__ QKVb, u16* __restrict__ Vt) {
    __shared__ u16 tile[64][65];
    const int t0 = blockIdx.x * 64, d0 = blockIdx.y * 64, bh = blockIdx.z;
    const int b = bh >> 4, h = bh & 15;
    const int tid = threadIdx.x;
#pragma unroll
    for (int i = 0; i < 16; i++) {
        int idx = tid + i * 256;
        int r = idx >> 6, c = idx & 63;                // r: t, c: d
        tile[r][c] = QKVb[(size_t)(b * T_ + t0 + r) * N3_ + 2 * C_ + h * 128 + d0 + c];
    }
    __syncthreads();
#pragma unroll
    for (int i = 0; i < 16; i++) {
        int idx = tid + i * 256;
        int r = idx >> 6, c = idx & 63;                // r: d, c: t
        Vt[((size_t)bh * 128 + d0 + r) * S_ + P_ + t0 + c] = tile[c][r];
    }
}

// past V f32 -> Vt[b,h,d,p]
__global__ void vpastT_kernel(const float* __restrict__ past_v, u16* __restrict__ Vt) {
    __shared__ float tile[64][65];
    const int p0 = blockIdx.x * 64, d0 = blockIdx.y * 64, bh = blockIdx.z;
    const int tid = threadIdx.x;
#pragma unroll
    for (int i = 0; i < 16; i++) {
        int idx = tid + i * 256;
        int r = idx >> 6, c = idx & 63;                // r: p, c: d
        tile[r][c] = past_v[((size_t)bh * P_ + p0 + r) * 128 + d0 + c];
    }
    __syncthreads();
#pragma unroll
    for (int i = 0; i < 16; i++) {
        int idx = tid + i * 256;
        int r = idx >> 6, c = idx & 63;                // r: d, c: p
        Vt[((size_t)bh * 128 + d0 + r) * S_ + p0 + c] = f2bf(tile[c][r]);
    }
}

// ---------------------------------------------------------------- GEMM (3-buf)
// C[M,N] = A[M,K] * Bt[N,K]^T ; bf16 in, OutT out.
// BM=256, BN=128, BK=64, NBUF=3 (LDS 144 KiB). 8 waves (4m x 2n), per-wave
// 64x64 C. Counted-vmcnt pipeline (T4): iteration t waits vmcnt(6) -- tile
// t+1's 6 loads STAY in flight across the barrier -- then issues tile t+2
// into buf[(t+2)%3] (its readers of tile t-1 completed before this barrier;
// lgkmcnt-complete reads precede each wave's barrier arrival). One barrier
// per K-step, no mid-loop drain. LDS rows 128 B, XOR-swizzle ((row&7)<<4)
// via pre-swizzled global source (linear LDS dest, rule #21).
template <typename OutT>
__global__ void __launch_bounds__(512, 1)
gemm3(const u16* __restrict__ A, const u16* __restrict__ Bt,
      OutT* __restrict__ Co, int Mdim, int Ndim, int Kdim) {
    __shared__ u16 lA[3 * 256 * 64];   // 96 KiB
    __shared__ u16 lB[3 * 128 * 64];   // 48 KiB
    const int nbx = Ndim >> 7;
    const int nwg = (Mdim >> 8) * nbx;
    int bid = blockIdx.x;
    int wg = (bid & 7) * (nwg >> 3) + (bid >> 3);      // XCD swizzle (nwg%8==0)
    const int bm = wg / nbx, bn = wg % nbx;
    const int m0 = bm << 8, n0 = bn << 7;
    const int tid = threadIdx.x;
    const int wave = tid >> 6, lane = tid & 63;
    const int mw = wave >> 1, nw = wave & 1;
    const int l15 = lane & 15, l4 = lane >> 4;

    f32x4 acc[4][4];
#pragma unroll
    for (int i = 0; i < 4; i++)
#pragma unroll
        for (int j = 0; j < 4; j++) acc[i][j] = (f32x4){0.f, 0.f, 0.f, 0.f};

    // staging sources: chunk cid = i*512 + tid; row = cid>>3, physical chunk
    // pc = cid&7 holds logical chunk pc^(row&7) (inverse-swizzled source).
    const u16* aSrc[4];
    const u16* bSrc[2];
#pragma unroll
    for (int i = 0; i < 4; i++) {
        int cid = i * 512 + tid;
        int r = cid >> 3, pc = cid & 7;
        aSrc[i] = A + (size_t)(m0 + r) * Kdim + ((pc ^ (r & 7)) << 3);
    }
#pragma unroll
    for (int i = 0; i < 2; i++) {
        int cid = i * 512 + tid;
        int r = cid >> 3, pc = cid & 7;
        bSrc[i] = Bt + (size_t)(n0 + r) * Kdim + ((pc ^ (r & 7)) << 3);
    }

#define STAGE3(bi, kt) do {                                                     \
    u16* _pa = lA + (bi) * 16384 + wave * 512;                                  \
    u16* _pb = lB + (bi) * 8192 + wave * 512;                                   \
    _Pragma("unroll")                                                           \
    for (int i = 0; i < 4; i++)                                                 \
        gload_lds16(aSrc[i] + (size_t)(kt) * 64, _pa + i * 4096);               \
    _Pragma("unroll")                                                           \
    for (int i = 0; i < 2; i++)                                                 \
        gload_lds16(bSrc[i] + (size_t)(kt) * 64, _pb + i * 4096);               \
} while (0)

    STAGE3(0, 0);
    STAGE3(1, 1);

    const int NT = Kdim >> 6;
    int bc = 0;
    for (int t = 0; t < NT; ++t) {
        if (t + 1 < NT) asm volatile("s_waitcnt vmcnt(6)" ::: "memory");
        else            asm volatile("s_waitcnt vmcnt(0)" ::: "memory");
        __builtin_amdgcn_s_barrier();
        asm volatile("" ::: "memory");
        if (t + 2 < NT) {
            int b2 = bc + 2; if (b2 >= 3) b2 -= 3;
            STAGE3(b2, t + 2);
        }
        const u16* la = lA + bc * 16384;
        const u16* lb = lB + bc * 8192;
        short8 af[4][2], bf[4][2];
#pragma unroll
        for (int i = 0; i < 4; i++)
#pragma unroll
            for (int kk = 0; kk < 2; kk++) {
                int r = mw * 64 + i * 16 + l15;
                int cb = (kk * 64 + l4 * 16) ^ ((r & 7) << 4);
                af[i][kk] = *(const short8*)&la[r * 64 + (cb >> 1)];
            }
#pragma unroll
        for (int j = 0; j < 4; j++)
#pragma unroll
            for (int kk = 0; kk < 2; kk++) {
                int r = nw * 64 + j * 16 + l15;
                int cb = (kk * 64 + l4 * 16) ^ ((r & 7) << 4);
                bf[j][kk] = *(const short8*)&lb[r * 64 + (cb >> 1)];
            }
        __builtin_amdgcn_s_setprio(1);
#pragma unroll
        for (int kk = 0; kk < 2; kk++)
#pragma unroll
            for (int i = 0; i < 4; i++)
#pragma unroll
                for (int j = 0; j < 4; j++)
                    acc[i][j] = mfma_bf16(af[i][kk], bf[j][kk], acc[i][j]);
        __builtin_amdgcn_s_setprio(0);
        __builtin_amdgcn_sched_barrier(0);   // rule #18: pin MFMA/lgkm here
        bc = bc + 1; if (bc >= 3) bc = 0;
    }
#undef STAGE3

    // epilogue
#pragma unroll
    for (int i = 0; i < 4; i++)
#pragma unroll
        for (int j = 0; j < 4; j++) {
            int row = m0 + mw * 64 + i * 16 + (l4 << 2);
            int col = n0 + nw * 64 + j * 16 + l15;
#pragma unroll
            for (int q = 0; q < 4; q++)
                storeC(&Co[(size_t)(row + q) * Ndim + col], acc[i][j][q]);
        }
}

// ---------------------------------------------------------------- attention
// m214-style: 8 waves x 32 q-rows = 256 q/block; one (b,h) slice per block.
// Swapped QK^T (mfma(K,Q)): P C-frag has q = lane&31, k reg-mapped -> softmax
// fully in-register (1 shfl_xor(32) per reduce). Swapped PV (mfma(V^T,P^T)):
// O^T C-frag has q = lane&31 -> rescale factor lane-local. No P LDS buffer.
// K/V double-buffered LDS, XOR-swizzle ((row&7)<<4) both-sides (rule #21).
__global__ void __launch_bounds__(512, 2)
attn_kernel(const u16* __restrict__ QKVb, const u16* __restrict__ Kc,
            const u16* __restrict__ Vt, u16* __restrict__ O) {
    __shared__ u16 ldsK[2][64 * 128];   // [buf][64 k][128 d], rows 256B
    __shared__ u16 ldsV[2][128 * 64];   // [buf][128 d][64 k], rows 128B

    int bid = blockIdx.x;                              // 256 blocks
    int wg = (bid & 7) * 32 + (bid >> 3);              // XCD swizzle (bijective)
    const int qc = wg & 7;                             // q-chunk (8 x 256 rows)
    const int bh = wg >> 3;
    const int b = bh >> 4, h = bh & 15;
    const int tid = threadIdx.x, wave = tid >> 6, lane = tid & 63;
    const int l31 = lane & 31, hi = lane >> 5;

    // staging constants (source pre-swizzled; LDS dest linear)
    const int krow = tid >> 4;                                         // 0..31
    const int kcol = (((tid & 15) << 4) ^ ((krow & 7) << 4)) >> 1;
    const int vrow = tid >> 3;                                         // 0..63
    const int vcol = (((tid & 7) << 4) ^ ((vrow & 7) << 4)) >> 1;

    const u16* Kbh = Kc + (size_t)bh * S_ * 128;
    const u16* Vbh = Vt + (size_t)bh * 128 * S_;

    const int tq = qc * 256 + wave * 32 + l31;         // this lane's q row
    // Q fragments: Q[q=l31][d = ks*16 + hi*8 + e], 8 x bf16x8
    short8 qf[8];
    {
        const u16* qp = QKVb + (size_t)(b * T_ + tq) * N3_ + h * 128 + hi * 8;
#pragma unroll
        for (int ks = 0; ks < 8; ks++) qf[ks] = *(const short8*)(qp + ks * 16);
    }

    f32x16 acco[4];                                    // O^T: col q=l31, row d
#pragma unroll
    for (int d = 0; d < 4; d++) acco[d] = (f32x16)(0.0f);
    float mrow = -1e30f, lrow = 0.f;                   // per-lane (q = l31)
    const float sl2 = 0.08838834764831845f * 1.4426950408889634f;

#define STAGE(bufi, tt) do {                                                    \
    const int _s0 = (tt) * 64;                                                  \
    gload_lds16(Kbh + (size_t)(_s0 + krow) * 128 + kcol,                        \
                (char*)&ldsK[bufi][0] + wave * 1024);                           \
    gload_lds16(Kbh + (size_t)(_s0 + krow + 32) * 128 + kcol,                   \
                (char*)&ldsK[bufi][0] + 8192 + wave * 1024);                    \
    gload_lds16(Vbh + (size_t)vrow * S_ + _s0 + vcol,                           \
                (char*)&ldsV[bufi][0] + wave * 1024);                           \
    gload_lds16(Vbh + (size_t)(vrow + 64) * S_ + _s0 + vcol,                    \
                (char*)&ldsV[bufi][0] + 8192 + wave * 1024);                    \
} while (0)

    STAGE(0, 0);
    __syncthreads();

    const int swz = (l31 & 7) << 4;                    // read-side swizzle

    for (int t = 0; t < S_ / 64; ++t) {
        const int cur = t & 1;
        if (t < S_ / 64 - 1) STAGE(cur ^ 1, t + 1);

        const u16* Kl = ldsK[cur];
        const u16* Vl = ldsV[cur];

        // ---- QK^T: p0 (k 0..31), p1 (k 32..63); contraction d ----
        f32x16 p0 = (f32x16)(0.0f), p1 = (f32x16)(0.0f);
        __builtin_amdgcn_s_setprio(1);
#pragma unroll
        for (int ks = 0; ks < 8; ks++) {
            const int cidx = (((ks * 32 + hi * 16) ^ swz) >> 1);
            short8 k0 = *(const short8*)&Kl[(l31 << 7) + cidx];
            short8 k1 = *(const short8*)&Kl[((32 + l31) << 7) + cidx];
            p0 = mfma32(k0, qf[ks], p0);
            p1 = mfma32(k1, qf[ks], p1);
        }
        __builtin_amdgcn_s_setprio(0);

        // ---- online softmax, in-register (q = l31) ----
        float pm = fmaxf(p0[0], p0[1]);
#pragma unroll
        for (int r = 2; r < 16; r++) pm = fmaxf(pm, p0[r]);
#pragma unroll
        for (int r = 0; r < 16; r++) pm = fmaxf(pm, p1[r]);
        pm = fmaxf(pm, __shfl_xor(pm, 32));
        float pmS = pm * sl2;
        if (!__all(pmS <= mrow + 8.0f)) {              // T13 defer-max
            float mn = fmaxf(mrow, pmS);
            float fac = exp2f(mrow - mn);
            mrow = mn;
            lrow *= fac;
#pragma unroll
            for (int d = 0; d < 4; d++)
#pragma unroll
                for (int r = 0; r < 16; r++) acco[d][r] *= fac;
        }
        float sum = 0.f;
#pragma unroll
        for (int r = 0; r < 16; r++) { p0[r] = exp2f(fmaf(p0[r], sl2, -mrow)); sum += p0[r]; }
#pragma unroll
        for (int r = 0; r < 16; r++) { p1[r] = exp2f(fmaf(p1[r], sl2, -mrow)); sum += p1[r]; }
        sum += __shfl_xor(sum, 32);
        lrow += sum;

        // ---- P (C-layout) -> PV B-frags, in-register (T12 via shfl) ----
        // k_local(reg,hi) = (reg&3) + 8*(reg>>2) + 4*hi; frag e -> k = ks*16+hi*8+e
        uint32 w[4][4];
#define PACK_HALF(pp, kh, ksout) do {                                           \
    uint32 A0 = pkbf(pp[(kh)*8 + 0], pp[(kh)*8 + 1]);                           \
    uint32 A1 = pkbf(pp[(kh)*8 + 2], pp[(kh)*8 + 3]);                           \
    uint32 B0 = pkbf(pp[(kh)*8 + 4], pp[(kh)*8 + 5]);                           \
    uint32 B1 = pkbf(pp[(kh)*8 + 6], pp[(kh)*8 + 7]);                           \
    uint32 sA0 = __shfl_xor(A0, 32), sA1 = __shfl_xor(A1, 32);                  \
    uint32 sB0 = __shfl_xor(B0, 32), sB1 = __shfl_xor(B1, 32);                  \
    w[ksout][0] = hi ? sB0 : A0;                                                \
    w[ksout][1] = hi ? sB1 : A1;                                                \
    w[ksout][2] = hi ? B0 : sA0;                                                \
    w[ksout][3] = hi ? B1 : sA1;                                                \
} while (0)
        PACK_HALF(p0, 0, 0);
        PACK_HALF(p0, 1, 1);
        PACK_HALF(p1, 0, 2);
        PACK_HALF(p1, 1, 3);
#undef PACK_HALF

        // ---- PV: O^T[d][q] += V^T[d][k] * P^T[k][q] ----
        __builtin_amdgcn_s_setprio(1);
#pragma unroll
        for (int ks = 0; ks < 4; ks++) {
            uint4v pw = {w[ks][0], w[ks][1], w[ks][2], w[ks][3]};
            short8 pf = __builtin_bit_cast(short8, pw);
            const int cidx = (((ks * 32 + hi * 16) ^ swz) >> 1);
#pragma unroll
            for (int dblk = 0; dblk < 4; dblk++) {
                short8 vf = *(const short8*)&Vl[((dblk * 32 + l31) << 6) + cidx];
                acco[dblk] = mfma32(vf, pf, acco[dblk]);
            }
        }
        __builtin_amdgcn_s_setprio(0);

        __syncthreads();   // readers done with cur; stage(cur^1) drained
    }
#undef STAGE

    // ---- epilogue: O[b*T+tq][h*128+d], d = dblk*32 + 8*j + 4*hi + {0..3} ----
    float rl = 1.0f / lrow;
    u16* Op = O + (size_t)(b * T_ + tq) * C_ + h * 128;
#pragma unroll
    for (int dblk = 0; dblk < 4; dblk++)
#pragma unroll
        for (int j = 0; j < 4; j++) {
            u16x4 o;
            o.x = f2bf(acco[dblk][4 * j + 0] * rl);
            o.y = f2bf(acco[dblk][4 * j + 1] * rl);
            o.z = f2bf(acco[dblk][4 * j + 2] * rl);
            o.w = f2bf(acco[dblk][4 * j + 3] * rl);
            *(u16x4*)(Op + dblk * 32 + j * 8 + hi * 4) = o;
        }
}

// ---------------------------------------------------------------- launch

extern "C" void kernel_launch(void* const* d_in, const int* in_sizes, int n_in,
                              void* d_out, int out_size, void* d_ws, size_t ws_size,
                              hipStream_t stream) {
    const float* x      = (const float*)d_in[0];
    const float* w_qkv  = (const float*)d_in[1];
    const float* w_out  = (const float*)d_in[2];
    const float* past_k = (const float*)d_in[3];
    const float* past_v = (const float*)d_in[4];
    float* out = (float*)d_out;

    char* ws = (char*)d_ws;
    u16* Xb    = (u16*)(ws);                            // 16 MB
    u16* Wqkvt = (u16*)(ws + 16777216);                 // 24 MB
    u16* Woutt = (u16*)(ws + 41943040);                 //  8 MB
    u16* QKVb  = (u16*)(ws + 50331648);                 // 48 MB
    u16* Kc    = (u16*)(ws + 100663296);                // 24 MB
    u16* Vt    = (u16*)(ws + 125829120);                // 24 MB
    u16* O     = (u16*)(ws + 150994944);                // 16 MB
    float* cosT = (float*)(ws + 167772160);             // 0.5 MB
    float* sinT = (float*)(ws + 168296448);             // 0.5 MB

    castx_kernel<<<(M_ * C_ / 4) / 256, 256, 0, stream>>>(x, Xb);
    wT_kernel<<<dim3(N3_ / 64, C_ / 64), 256, 0, stream>>>(w_qkv, Wqkvt, N3_, C_);
    wT_kernel<<<dim3(C_ / 64, C_ / 64), 256, 0, stream>>>(w_out, Woutt, C_, C_);
    rope_table_kernel<<<(T_ * 64) / 256, 256, 0, stream>>>(cosT, sinT);

    gemm3<u16><<<(M_ / 256) * (N3_ / 128), 512, 0, stream>>>(Xb, Wqkvt, QKVb, M_, N3_, C_);

    rope_qk_kernel<<<(B_ * T_ * H_ * 64) / 256, 256, 0, stream>>>(QKVb, Kc, cosT, sinT);
    pastk_kernel<<<(B_ * H_ * P_ * D_) / 256, 256, 0, stream>>>(past_k, Kc);
    vnewT_kernel<<<dim3(T_ / 64, 2, B_ * H_), 256, 0, stream>>>(QKVb, Vt);
    vpastT_kernel<<<dim3(P_ / 64, 2, B_ * H_), 256, 0, stream>>>(past_v, Vt);

    attn_kernel<<<256, 512, 0, stream>>>(QKVb, Kc, Vt, O);

    gemm3<float><<<(M_ / 256) * (C_ / 128), 512, 0, stream>>>(O, Woutt, out, M_, C_, C_);
}

// Round 6
// 394.024 us; speedup vs baseline: 1.0781x; 1.0148x over previous
//
#include <hip/hip_runtime.h>
#include <stdint.h>

#define B_ 2
#define T_ 2048
#define P_ 1024
#define H_ 16
#define D_ 128
#define C_ 2048
#define S_ 3072   // P_ + T_
#define M_ 4096   // B_*T_
#define N3_ 6144  // 3*C_

typedef unsigned short u16;
typedef unsigned int uint32;
typedef __attribute__((ext_vector_type(8))) short short8;
typedef __attribute__((ext_vector_type(8))) __bf16 bf16x8;
typedef __attribute__((ext_vector_type(4))) float f32x4;
typedef __attribute__((ext_vector_type(16))) float f32x16;
typedef __attribute__((ext_vector_type(4))) unsigned short u16x4;
typedef __attribute__((ext_vector_type(4))) unsigned int uint4v;

static __device__ __forceinline__ float bf2f(u16 h) {
    union { unsigned int u; float f; } x; x.u = ((unsigned int)h) << 16; return x.f;
}
static __device__ __forceinline__ u16 f2bf(float f) {
    return __builtin_bit_cast(u16, (__bf16)f);   // v_cvt: RNE, 1 op
}
static __device__ __forceinline__ uint32 pkbf(float x, float y) {
    return (uint32)f2bf(x) | ((uint32)f2bf(y) << 16);
}

static __device__ __forceinline__ f32x4 mfma_bf16(short8 a, short8 b, f32x4 c) {
    return __builtin_amdgcn_mfma_f32_16x16x32_bf16(
        __builtin_bit_cast(bf16x8, a), __builtin_bit_cast(bf16x8, b), c, 0, 0, 0);
}
static __device__ __forceinline__ f32x16 mfma32(short8 a, short8 b, f32x16 c) {
    return __builtin_amdgcn_mfma_f32_32x32x16_bf16(
        __builtin_bit_cast(bf16x8, a), __builtin_bit_cast(bf16x8, b), c, 0, 0, 0);
}

typedef __attribute__((address_space(3))) unsigned int lds_u32;
typedef const __attribute__((address_space(1))) unsigned int glb_u32;
static __device__ __forceinline__ void gload_lds16(const void* g, void* l) {
    __builtin_amdgcn_global_load_lds((glb_u32*)g, (lds_u32*)l, 16, 0, 0);
}

static __device__ __forceinline__ void storeC(float* p, float v) { *p = v; }
static __device__ __forceinline__ void storeC(u16* p, float v) { *p = f2bf(v); }

// ---------------------------------------------------------------- prep kernels

__global__ void castx_kernel(const float* __restrict__ x, u16* __restrict__ Xb) {
    int idx = blockIdx.x * 256 + threadIdx.x;          // over (M_*C_)/4
    const float4 v = ((const float4*)x)[idx];
    u16x4 o;
    o.x = f2bf(v.x); o.y = f2bf(v.y); o.z = f2bf(v.z); o.w = f2bf(v.w);
    ((u16x4*)Xb)[idx] = o;
}

// W[K,N] f32 -> Wt[N,K] bf16, 64x64 LDS tiles
__global__ void wT_kernel(const float* __restrict__ W, u16* __restrict__ Wt,
                          int Ndim, int Kdim) {
    __shared__ float tile[64][65];
    const int n0 = blockIdx.x * 64, k0 = blockIdx.y * 64;
    const int tid = threadIdx.x;
#pragma unroll
    for (int i = 0; i < 16; i++) {
        int idx = tid + i * 256;
        int r = idx >> 6, c = idx & 63;                // r: k, c: n
        tile[r][c] = W[(size_t)(k0 + r) * Ndim + n0 + c];
    }
    __syncthreads();
#pragma unroll
    for (int i = 0; i < 16; i++) {
        int idx = tid + i * 256;
        int r = idx >> 6, c = idx & 63;                // r: n, c: k
        Wt[(size_t)(n0 + r) * Kdim + k0 + c] = f2bf(tile[c][r]);
    }
}

__global__ void rope_table_kernel(float* __restrict__ cosT, float* __restrict__ sinT) {
    int idx = blockIdx.x * 256 + threadIdx.x;          // T_*64
    int t = idx >> 6, d = idx & 63;
    float inv = powf(10000.0f, -(float)d * (1.0f / 64.0f));
    float ang = (float)(P_ + t) * inv;
    cosT[idx] = cosf(ang);
    sinT[idx] = sinf(ang);
}

// RoPE Q in place; RoPE K and scatter into Kc[b,h,P_+t,d]
__global__ void rope_qk_kernel(u16* __restrict__ QKVb, u16* __restrict__ Kc,
                               const float* __restrict__ cosT,
                               const float* __restrict__ sinT) {
    int idx = blockIdx.x * 256 + threadIdx.x;          // B_*T_*H_*64
    int d = idx & 63;
    int h = (idx >> 6) & 15;
    int t = (idx >> 10) & 2047;
    int b = idx >> 21;
    size_t rowoff = (size_t)(b * T_ + t) * N3_;
    float c = cosT[(t << 6) + d], s = sinT[(t << 6) + d];
    {   // Q
        u16* p1 = QKVb + rowoff + h * 128 + d;
        float x1 = bf2f(p1[0]), x2 = bf2f(p1[64]);
        p1[0]  = f2bf(x1 * c - x2 * s);
        p1[64] = f2bf(x2 * c + x1 * s);
    }
    {   // K -> cache
        const u16* p1 = QKVb + rowoff + C_ + h * 128 + d;
        float x1 = bf2f(p1[0]), x2 = bf2f(p1[64]);
        u16* o = Kc + ((size_t)(b * H_ + h) * S_ + P_ + t) * 128 + d;
        o[0]  = f2bf(x1 * c - x2 * s);
        o[64] = f2bf(x2 * c + x1 * s);
    }
}

__global__ void pastk_kernel(const float* __restrict__ past_k, u16* __restrict__ Kc) {
    int idx = blockIdx.x * 256 + threadIdx.x;          // B_*H_*P_*D_
    int d = idx & 127;
    int p = (idx >> 7) & 1023;
    int bh = idx >> 17;
    Kc[((size_t)bh * S_ + p) * 128 + d] = f2bf(past_k[idx]);
}

// new V (bf16 in QKVb) -> Vt[b,h,d,P_+t]
__global__ void vnewT_kernel(const u16* __restrict__ QKVb, u16* __restrict__ Vt) {
    __shared__ u16 tile[64][65];
    const int t0 = blockIdx.x * 64, d0 = blockIdx.y * 64, bh = blockIdx.z;
    const int b = bh >> 4, h = bh & 15;
    const int tid = threadIdx.x;
#pragma unroll
    for (int i = 0; i < 16; i++) {
        int idx = tid + i * 256;
        int r = idx >> 6, c = idx & 63;                // r: t, c: d
        tile[r][c] = QKVb[(size_t)(b * T_ + t0 + r) * N3_ + 2 * C_ + h * 128 + d0 + c];
    }
    __syncthreads();
#pragma unroll
    for (int i = 0; i < 16; i++) {
        int idx = tid + i * 256;
        int r = idx >> 6, c = idx & 63;                // r: d, c: t
        Vt[((size_t)bh * 128 + d0 + r) * S_ + P_ + t0 + c] = tile[c][r];
    }
}

// past V f32 -> Vt[b,h,d,p]
__global__ void vpastT_kernel(const float* __restrict__ past_v, u16* __restrict__ Vt) {
    __shared__ float tile[64][65];
    const int p0 = blockIdx.x * 64, d0 = blockIdx.y * 64, bh = blockIdx.z;
    const int tid = threadIdx.x;
#pragma unroll
    for (int i = 0; i < 16; i++) {
        int idx = tid + i * 256;
        int r = idx >> 6, c = idx & 63;                // r: p, c: d
        tile[r][c] = past_v[((size_t)bh * P_ + p0 + r) * 128 + d0 + c];
    }
    __syncthreads();
#pragma unroll
    for (int i = 0; i < 16; i++) {
        int idx = tid + i * 256;
        int r = idx >> 6, c = idx & 63;                // r: d, c: p
        Vt[((size_t)bh * 128 + d0 + r) * S_ + p0 + c] = f2bf(tile[c][r]);
    }
}

// ---------------------------------------------------------------- GEMM (3-buf)
// C[M,N] = A[M,K] * Bt[N,K]^T ; bf16 in, OutT out.
// BM=256, BN=128, BK=64, NBUF=3 (LDS 144 KiB). 8 waves (4m x 2n), per-wave
// 64x64 C. Counted-vmcnt pipeline (T4): iteration t waits vmcnt(6) -- tile
// t+1's 6 loads STAY in flight across the barrier -- then issues tile t+2
// into buf[(t+2)%3]. One barrier per K-step, no mid-loop drain. LDS rows
// 128 B, XOR-swizzle ((row&7)<<4) via pre-swizzled global source (rule #21).
template <typename OutT>
__global__ void __launch_bounds__(512, 1)
gemm3(const u16* __restrict__ A, const u16* __restrict__ Bt,
      OutT* __restrict__ Co, int Mdim, int Ndim, int Kdim) {
    __shared__ u16 lA[3 * 256 * 64];   // 96 KiB
    __shared__ u16 lB[3 * 128 * 64];   // 48 KiB
    const int nbx = Ndim >> 7;
    const int nwg = (Mdim >> 8) * nbx;
    int bid = blockIdx.x;
    int wg = (bid & 7) * (nwg >> 3) + (bid >> 3);      // XCD swizzle (nwg%8==0)
    const int bm = wg / nbx, bn = wg % nbx;
    const int m0 = bm << 8, n0 = bn << 7;
    const int tid = threadIdx.x;
    const int wave = tid >> 6, lane = tid & 63;
    const int mw = wave >> 1, nw = wave & 1;
    const int l15 = lane & 15, l4 = lane >> 4;

    f32x4 acc[4][4];
#pragma unroll
    for (int i = 0; i < 4; i++)
#pragma unroll
        for (int j = 0; j < 4; j++) acc[i][j] = (f32x4){0.f, 0.f, 0.f, 0.f};

    // staging sources: chunk cid = i*512 + tid; row = cid>>3, physical chunk
    // pc = cid&7 holds logical chunk pc^(row&7) (inverse-swizzled source).
    const u16* aSrc[4];
    const u16* bSrc[2];
#pragma unroll
    for (int i = 0; i < 4; i++) {
        int cid = i * 512 + tid;
        int r = cid >> 3, pc = cid & 7;
        aSrc[i] = A + (size_t)(m0 + r) * Kdim + ((pc ^ (r & 7)) << 3);
    }
#pragma unroll
    for (int i = 0; i < 2; i++) {
        int cid = i * 512 + tid;
        int r = cid >> 3, pc = cid & 7;
        bSrc[i] = Bt + (size_t)(n0 + r) * Kdim + ((pc ^ (r & 7)) << 3);
    }

#define STAGE3(bi, kt) do {                                                     \
    u16* _pa = lA + (bi) * 16384 + wave * 512;                                  \
    u16* _pb = lB + (bi) * 8192 + wave * 512;                                   \
    _Pragma("unroll")                                                           \
    for (int i = 0; i < 4; i++)                                                 \
        gload_lds16(aSrc[i] + (size_t)(kt) * 64, _pa + i * 4096);               \
    _Pragma("unroll")                                                           \
    for (int i = 0; i < 2; i++)                                                 \
        gload_lds16(bSrc[i] + (size_t)(kt) * 64, _pb + i * 4096);               \
} while (0)

    STAGE3(0, 0);
    STAGE3(1, 1);

    const int NT = Kdim >> 6;
    int bc = 0;
    for (int t = 0; t < NT; ++t) {
        if (t + 1 < NT) asm volatile("s_waitcnt vmcnt(6)" ::: "memory");
        else            asm volatile("s_waitcnt vmcnt(0)" ::: "memory");
        __builtin_amdgcn_s_barrier();
        asm volatile("" ::: "memory");
        if (t + 2 < NT) {
            int b2 = bc + 2; if (b2 >= 3) b2 -= 3;
            STAGE3(b2, t + 2);
        }
        const u16* la = lA + bc * 16384;
        const u16* lb = lB + bc * 8192;
        short8 af[4][2], bf[4][2];
#pragma unroll
        for (int i = 0; i < 4; i++)
#pragma unroll
            for (int kk = 0; kk < 2; kk++) {
                int r = mw * 64 + i * 16 + l15;
                int cb = (kk * 64 + l4 * 16) ^ ((r & 7) << 4);
                af[i][kk] = *(const short8*)&la[r * 64 + (cb >> 1)];
            }
#pragma unroll
        for (int j = 0; j < 4; j++)
#pragma unroll
            for (int kk = 0; kk < 2; kk++) {
                int r = nw * 64 + j * 16 + l15;
                int cb = (kk * 64 + l4 * 16) ^ ((r & 7) << 4);
                bf[j][kk] = *(const short8*)&lb[r * 64 + (cb >> 1)];
            }
        __builtin_amdgcn_s_setprio(1);
#pragma unroll
        for (int kk = 0; kk < 2; kk++)
#pragma unroll
            for (int i = 0; i < 4; i++)
#pragma unroll
                for (int j = 0; j < 4; j++)
                    acc[i][j] = mfma_bf16(af[i][kk], bf[j][kk], acc[i][j]);
        __builtin_amdgcn_s_setprio(0);
        __builtin_amdgcn_sched_barrier(0);   // rule #18: pin MFMA/lgkm here
        bc = bc + 1; if (bc >= 3) bc = 0;
    }
#undef STAGE3

    // epilogue
#pragma unroll
    for (int i = 0; i < 4; i++)
#pragma unroll
        for (int j = 0; j < 4; j++) {
            int row = m0 + mw * 64 + i * 16 + (l4 << 2);
            int col = n0 + nw * 64 + j * 16 + l15;
#pragma unroll
            for (int q = 0; q < 4; q++)
                storeC(&Co[(size_t)(row + q) * Ndim + col], acc[i][j][q]);
        }
}

// ---------------------------------------------------------------- attention
// 4 waves x 32 q-rows = 128 q/block; 512 blocks -> 2 independent blocks/CU
// (m114: cross-block MFMA/VALU overlap; R5's 256-block version was 1
// barrier-locked block/CU). Swapped QK^T / swapped PV, in-register softmax,
// T13 defer-max, K/V dbuf LDS with XOR-swizzle (rule #21).
__global__ void __launch_bounds__(256, 2)
attn_kernel(const u16* __restrict__ QKVb, const u16* __restrict__ Kc,
            const u16* __restrict__ Vt, u16* __restrict__ O) {
    __shared__ u16 ldsK[2][64 * 128];   // [buf][64 k][128 d], rows 256B
    __shared__ u16 ldsV[2][128 * 64];   // [buf][128 d][64 k], rows 128B

    int bid = blockIdx.x;                              // 512 blocks
    int wg = (bid & 7) * 64 + (bid >> 3);              // XCD swizzle (bijective)
    const int qc = wg & 15;                            // q-chunk (16 x 128 rows)
    const int bh = wg >> 4;
    const int b = bh >> 4, h = bh & 15;
    const int tid = threadIdx.x, wave = tid >> 6, lane = tid & 63;
    const int l31 = lane & 31, hi = lane >> 5;

    // staging constants (256 thr): source pre-swizzled; LDS dest linear.
    // K: chunk = tid + i*256, row = (tid>>4)+16i (row&7 const), 16 chunks/row.
    // V: chunk = tid + i*256, row = (tid>>3)+32i (row&7 const),  8 chunks/row.
    const int krow = tid >> 4;                                         // 0..15
    const int kcol = (((tid & 15) << 4) ^ ((krow & 7) << 4)) >> 1;
    const int vrow = tid >> 3;                                         // 0..31
    const int vcol = (((tid & 7) << 4) ^ ((vrow & 7) << 4)) >> 1;

    const u16* Kbh = Kc + (size_t)bh * S_ * 128;
    const u16* Vbh = Vt + (size_t)bh * 128 * S_;

    const int tq = qc * 128 + wave * 32 + l31;         // this lane's q row
    // Q fragments: Q[q=l31][d = ks*16 + hi*8 + e], 8 x bf16x8
    short8 qf[8];
    {
        const u16* qp = QKVb + (size_t)(b * T_ + tq) * N3_ + h * 128 + hi * 8;
#pragma unroll
        for (int ks = 0; ks < 8; ks++) qf[ks] = *(const short8*)(qp + ks * 16);
    }

    f32x16 acco[4];                                    // O^T: col q=l31, row d
#pragma unroll
    for (int d = 0; d < 4; d++) acco[d] = (f32x16)(0.0f);
    float mrow = -1e30f, lrow = 0.f;                   // per-lane (q = l31)
    const float sl2 = 0.08838834764831845f * 1.4426950408889634f;

#define STAGE(bufi, tt) do {                                                    \
    const int _s0 = (tt) * 64;                                                  \
    _Pragma("unroll")                                                           \
    for (int i = 0; i < 4; i++)                                                 \
        gload_lds16(Kbh + (size_t)(_s0 + krow + i * 16) * 128 + kcol,           \
                    (char*)&ldsK[bufi][0] + i * 4096 + wave * 1024);            \
    _Pragma("unroll")                                                           \
    for (int i = 0; i < 4; i++)                                                 \
        gload_lds16(Vbh + (size_t)(vrow + i * 32) * S_ + _s0 + vcol,            \
                    (char*)&ldsV[bufi][0] + i * 4096 + wave * 1024);            \
} while (0)

    STAGE(0, 0);
    __syncthreads();

    const int swz = (l31 & 7) << 4;                    // read-side swizzle

    for (int t = 0; t < S_ / 64; ++t) {
        const int cur = t & 1;
        if (t < S_ / 64 - 1) STAGE(cur ^ 1, t + 1);

        const u16* Kl = ldsK[cur];
        const u16* Vl = ldsV[cur];

        // ---- QK^T: p0 (k 0..31), p1 (k 32..63); contraction d ----
        f32x16 p0 = (f32x16)(0.0f), p1 = (f32x16)(0.0f);
        __builtin_amdgcn_s_setprio(1);
#pragma unroll
        for (int ks = 0; ks < 8; ks++) {
            const int cidx = (((ks * 32 + hi * 16) ^ swz) >> 1);
            short8 k0 = *(const short8*)&Kl[(l31 << 7) + cidx];
            short8 k1 = *(const short8*)&Kl[((32 + l31) << 7) + cidx];
            p0 = mfma32(k0, qf[ks], p0);
            p1 = mfma32(k1, qf[ks], p1);
        }
        __builtin_amdgcn_s_setprio(0);

        // ---- online softmax, in-register (q = l31) ----
        float pm = fmaxf(p0[0], p0[1]);
#pragma unroll
        for (int r = 2; r < 16; r++) pm = fmaxf(pm, p0[r]);
#pragma unroll
        for (int r = 0; r < 16; r++) pm = fmaxf(pm, p1[r]);
        pm = fmaxf(pm, __shfl_xor(pm, 32));
        float pmS = pm * sl2;
        if (!__all(pmS <= mrow + 8.0f)) {              // T13 defer-max
            float mn = fmaxf(mrow, pmS);
            float fac = exp2f(mrow - mn);
            mrow = mn;
            lrow *= fac;
#pragma unroll
            for (int d = 0; d < 4; d++)
#pragma unroll
                for (int r = 0; r < 16; r++) acco[d][r] *= fac;
        }
        float sum = 0.f;
#pragma unroll
        for (int r = 0; r < 16; r++) { p0[r] = exp2f(fmaf(p0[r], sl2, -mrow)); sum += p0[r]; }
#pragma unroll
        for (int r = 0; r < 16; r++) { p1[r] = exp2f(fmaf(p1[r], sl2, -mrow)); sum += p1[r]; }
        sum += __shfl_xor(sum, 32);
        lrow += sum;

        // ---- P (C-layout) -> PV B-frags, in-register (T12 via shfl) ----
        // k_local(reg,hi) = (reg&3) + 8*(reg>>2) + 4*hi; frag e -> k = ks*16+hi*8+e
        uint32 w[4][4];
#define PACK_HALF(pp, kh, ksout) do {                                           \
    uint32 A0 = pkbf(pp[(kh)*8 + 0], pp[(kh)*8 + 1]);                           \
    uint32 A1 = pkbf(pp[(kh)*8 + 2], pp[(kh)*8 + 3]);                           \
    uint32 B0 = pkbf(pp[(kh)*8 + 4], pp[(kh)*8 + 5]);                           \
    uint32 B1 = pkbf(pp[(kh)*8 + 6], pp[(kh)*8 + 7]);                           \
    uint32 sA0 = __shfl_xor(A0, 32), sA1 = __shfl_xor(A1, 32);                  \
    uint32 sB0 = __shfl_xor(B0, 32), sB1 = __shfl_xor(B1, 32);                  \
    w[ksout][0] = hi ? sB0 : A0;                                                \
    w[ksout][1] = hi ? sB1 : A1;                                                \
    w[ksout][2] = hi ? B0 : sA0;                                                \
    w[ksout][3] = hi ? B1 : sA1;                                                \
} while (0)
        PACK_HALF(p0, 0, 0);
        PACK_HALF(p0, 1, 1);
        PACK_HALF(p1, 0, 2);
        PACK_HALF(p1, 1, 3);
#undef PACK_HALF

        // ---- PV: O^T[d][q] += V^T[d][k] * P^T[k][q] ----
        __builtin_amdgcn_s_setprio(1);
#pragma unroll
        for (int ks = 0; ks < 4; ks++) {
            uint4v pw = {w[ks][0], w[ks][1], w[ks][2], w[ks][3]};
            short8 pf = __builtin_bit_cast(short8, pw);
            const int cidx = (((ks * 32 + hi * 16) ^ swz) >> 1);
#pragma unroll
            for (int dblk = 0; dblk < 4; dblk++) {
                short8 vf = *(const short8*)&Vl[((dblk * 32 + l31) << 6) + cidx];
                acco[dblk] = mfma32(vf, pf, acco[dblk]);
            }
        }
        __builtin_amdgcn_s_setprio(0);

        __syncthreads();   // readers done with cur; stage(cur^1) drained
    }
#undef STAGE

    // ---- epilogue: O[b*T+tq][h*128+d], d = dblk*32 + 8*j + 4*hi + {0..3} ----
    float rl = 1.0f / lrow;
    u16* Op = O + (size_t)(b * T_ + tq) * C_ + h * 128;
#pragma unroll
    for (int dblk = 0; dblk < 4; dblk++)
#pragma unroll
        for (int j = 0; j < 4; j++) {
            u16x4 o;
            o.x = f2bf(acco[dblk][4 * j + 0] * rl);
            o.y = f2bf(acco[dblk][4 * j + 1] * rl);
            o.z = f2bf(acco[dblk][4 * j + 2] * rl);
            o.w = f2bf(acco[dblk][4 * j + 3] * rl);
            *(u16x4*)(Op + dblk * 32 + j * 8 + hi * 4) = o;
        }
}

// ---------------------------------------------------------------- launch

extern "C" void kernel_launch(void* const* d_in, const int* in_sizes, int n_in,
                              void* d_out, int out_size, void* d_ws, size_t ws_size,
                              hipStream_t stream) {
    const float* x      = (const float*)d_in[0];
    const float* w_qkv  = (const float*)d_in[1];
    const float* w_out  = (const float*)d_in[2];
    const float* past_k = (const float*)d_in[3];
    const float* past_v = (const float*)d_in[4];
    float* out = (float*)d_out;

    char* ws = (char*)d_ws;
    u16* Xb    = (u16*)(ws);                            // 16 MB
    u16* Wqkvt = (u16*)(ws + 16777216);                 // 24 MB
    u16* Woutt = (u16*)(ws + 41943040);                 //  8 MB
    u16* QKVb  = (u16*)(ws + 50331648);                 // 48 MB
    u16* Kc    = (u16*)(ws + 100663296);                // 24 MB
    u16* Vt    = (u16*)(ws + 125829120);                // 24 MB
    u16* O     = (u16*)(ws + 150994944);                // 16 MB
    float* cosT = (float*)(ws + 167772160);             // 0.5 MB
    float* sinT = (float*)(ws + 168296448);             // 0.5 MB

    castx_kernel<<<(M_ * C_ / 4) / 256, 256, 0, stream>>>(x, Xb);
    wT_kernel<<<dim3(N3_ / 64, C_ / 64), 256, 0, stream>>>(w_qkv, Wqkvt, N3_, C_);
    wT_kernel<<<dim3(C_ / 64, C_ / 64), 256, 0, stream>>>(w_out, Woutt, C_, C_);
    rope_table_kernel<<<(T_ * 64) / 256, 256, 0, stream>>>(cosT, sinT);

    gemm3<u16><<<(M_ / 256) * (N3_ / 128), 512, 0, stream>>>(Xb, Wqkvt, QKVb, M_, N3_, C_);

    rope_qk_kernel<<<(B_ * T_ * H_ * 64) / 256, 256, 0, stream>>>(QKVb, Kc, cosT, sinT);
    pastk_kernel<<<(B_ * H_ * P_ * D_) / 256, 256, 0, stream>>>(past_k, Kc);
    vnewT_kernel<<<dim3(T_ / 64, 2, B_ * H_), 256, 0, stream>>>(QKVb, Vt);
    vpastT_kernel<<<dim3(P_ / 64, 2, B_ * H_), 256, 0, stream>>>(past_v, Vt);

    attn_kernel<<<512, 256, 0, stream>>>(QKVb, Kc, Vt, O);

    gemm3<float><<<(M_ / 256) * (C_ / 128), 512, 0, stream>>>(O, Woutt, out, M_, C_, C_);
}